// Round 1
// baseline (299.883 us; speedup 1.0000x reference)
//
#include <hip/hip_runtime.h>

// Problem constants (from reference)
#define B_    4
#define S_    2048
#define V_    50257
#define NB_   32
#define BS_   (B_ * S_)            // 8192 rows
static_assert((long long)BS_ * V_ % 4 == 0, "flat onehot must be float4-divisible");

// Kernel 1: streaming scan of the flat one-hot tensor.
// Every row has exactly one nonzero (==1.0f). Finder writes its column to tid[row].
__global__ __launch_bounds__(256) void find_tokens_kernel(
    const float4* __restrict__ onehot4, long long n4, int* __restrict__ tid)
{
    long long i = (long long)blockIdx.x * blockDim.x + threadIdx.x;
    long long stride = (long long)gridDim.x * blockDim.x;
    for (; i < n4; i += stride) {
        float4 v = onehot4[i];
        // rare branch: ~8192 hits out of ~103M vectors
        if (v.x != 0.0f || v.y != 0.0f || v.z != 0.0f || v.w != 0.0f) {
            long long base = i * 4;
            float vals[4] = {v.x, v.y, v.z, v.w};
            #pragma unroll
            for (int k = 0; k < 4; ++k) {
                if (vals[k] != 0.0f) {
                    long long idx = base + k;
                    int row = (int)(idx / V_);          // compiler: magic-mul
                    int col = (int)(idx - (long long)row * V_);
                    tid[row] = col;
                }
            }
        }
    }
}

// Kernel 2: per row, gather prototypes[n, tid], add gumbel, softmax(32),
// straight-through hard one-hot. One thread per row, all in registers.
__global__ __launch_bounds__(256) void gumbel_hard_kernel(
    const float* __restrict__ proto,     // [NB, V]
    const float* __restrict__ gumbel,    // [BS, NB]
    const int*   __restrict__ tid,       // [BS]
    float*       __restrict__ out)       // [BS, NB]
{
    int row = blockIdx.x * blockDim.x + threadIdx.x;
    if (row >= BS_) return;
    int t = tid[row];

    // vectorized gumbel load: 32 floats = 8 float4 (row*128B is 16B aligned)
    float g[NB_];
    {
        const float4* g4 = reinterpret_cast<const float4*>(gumbel + (long long)row * NB_);
        #pragma unroll
        for (int q = 0; q < NB_ / 4; ++q) {
            float4 v = g4[q];
            g[q * 4 + 0] = v.x; g[q * 4 + 1] = v.y;
            g[q * 4 + 2] = v.z; g[q * 4 + 3] = v.w;
        }
    }

    float z[NB_];
    float m = -1e30f;
    int   am = 0;
    #pragma unroll
    for (int n = 0; n < NB_; ++n) {
        float s = proto[(long long)n * V_ + t];
        float zn = s / 0.07f + g[n];      // logits/TEMP + gumbel, tau=1
        z[n] = zn;
        if (zn > m) { m = zn; am = n; }   // strict > => first max (matches argmax)
    }

    float e[NB_];
    float sum = 0.0f;
    #pragma unroll
    for (int n = 0; n < NB_; ++n) {
        e[n] = __expf(z[n] - m);
        sum += e[n];
    }
    float inv = 1.0f / sum;

    float4* o4 = reinterpret_cast<float4*>(out + (long long)row * NB_);
    #pragma unroll
    for (int q = 0; q < NB_ / 4; ++q) {
        float4 v;
        float r[4];
        #pragma unroll
        for (int k = 0; k < 4; ++k) {
            int n = q * 4 + k;
            float y = e[n] * inv;
            float h = (n == am) ? 1.0f : 0.0f;
            r[k] = (h - y) + y;           // reproduce straight-through arithmetic
        }
        v.x = r[0]; v.y = r[1]; v.z = r[2]; v.w = r[3];
        o4[q] = v;
    }
}

extern "C" void kernel_launch(void* const* d_in, const int* in_sizes, int n_in,
                              void* d_out, int out_size, void* d_ws, size_t ws_size,
                              hipStream_t stream)
{
    const float* onehot = (const float*)d_in[0];   // [B,S,V] f32
    const float* proto  = (const float*)d_in[1];   // [NB,V] f32
    const float* gumbel = (const float*)d_in[2];   // [B,S,NB] f32
    float* out = (float*)d_out;                    // [B,S,NB] f32
    int* tid = (int*)d_ws;                         // 8192 ints scratch

    long long n4 = ((long long)BS_ * V_) / 4;      // 102,926,336 float4s

    // memory-bound scan: ~4096 blocks x 256 threads, grid-stride
    find_tokens_kernel<<<4096, 256, 0, stream>>>(
        reinterpret_cast<const float4*>(onehot), n4, tid);

    gumbel_hard_kernel<<<(BS_ + 255) / 256, 256, 0, stream>>>(
        proto, gumbel, tid, out);
}